// Round 6
// baseline (209.100 us; speedup 1.0000x reference)
//
#include <hip/hip_runtime.h>
#include <hip/hip_bf16.h>
#include <math.h>

typedef __bf16 bf16_t;
typedef __bf16 bf16x8 __attribute__((ext_vector_type(8)));
typedef __bf16 bf16x4 __attribute__((ext_vector_type(4)));
typedef float floatx4 __attribute__((ext_vector_type(4)));

#define N_ROWS 4096
#define DIM 512
#define LAM 0.5f

#define GLOBAL_AS(p) ((const __attribute__((address_space(1))) void*)(p))
#define LDS_AS(p) ((__attribute__((address_space(3))) void*)(p))

// One wave per row: L2-normalize a 512-elem fp32 row, emit bf16 (linear layout).
// Thread 0 of block 0 zero-inits the scalar output (harness poisons it).
__global__ __launch_bounds__(256) void normalize_kernel(
    const float* __restrict__ ei, const float* __restrict__ ej,
    bf16_t* __restrict__ Z, float* __restrict__ out) {
    if (blockIdx.x == 0 && threadIdx.x == 0) out[0] = 0.0f;
    const int row  = blockIdx.x * 4 + (threadIdx.x >> 6);   // [0, 8192)
    const int lane = threadIdx.x & 63;
    const float* __restrict__ src = (row < N_ROWS)
        ? (ei + (size_t)row * DIM)
        : (ej + (size_t)(row - N_ROWS) * DIM);
    const float4* src4 = (const float4*)src;
    float4 v0 = src4[lane];
    float4 v1 = src4[lane + 64];
    float s = v0.x*v0.x + v0.y*v0.y + v0.z*v0.z + v0.w*v0.w
            + v1.x*v1.x + v1.y*v1.y + v1.z*v1.z + v1.w*v1.w;
    #pragma unroll
    for (int off = 32; off; off >>= 1) s += __shfl_xor(s, off);
    const float r = rsqrtf(s);
    bf16x4 o0 = { (bf16_t)(v0.x*r), (bf16_t)(v0.y*r), (bf16_t)(v0.z*r), (bf16_t)(v0.w*r) };
    bf16x4 o1 = { (bf16_t)(v1.x*r), (bf16_t)(v1.y*r), (bf16_t)(v1.z*r), (bf16_t)(v1.w*r) };
    bf16x4* dst = (bf16x4*)(Z + (size_t)row * DIM);
    dst[lane]      = o0;
    dst[lane + 64] = o1;
}

// Fused S = Z.Z^T + loss.  EXACT round-1 structure (bf16, BK=32, 2D grid,
// 128x128 block, 4 waves 2x2, 16x16x32 bf16 MFMA) with ONE change: the
// staging lane-map is lane -> (row = lane&15, kchunk = lane>>4), which makes
// the LDS tile chunk-column-major.  Fragment reads (fixed q) become 16 lanes
// x contiguous 256 B -> 2-way bank aliasing only (free), vs round 1's 8-way
// conflicts (4.26M cycles).  global_load_lds constraints still hold: LDS
// placement is lane-contiguous; global footprint per instruction is the same
// 16 rows x 64 B (lane-order permutation of fetches proven harmless in R3/R4).
// Positives fused into the epilogue (R2's scheme); upper-triangle blocks only.
__global__ __launch_bounds__(256) void simloss_kernel(
    const bf16_t* __restrict__ Z, float* __restrict__ out) {
    const int bm = blockIdx.x, bn = blockIdx.y;
    if (bn < bm) return;                      // symmetry: skip lower triangle
    const int t = threadIdx.x;
    const int w = t >> 6, lane = t & 63;
    const int q = lane >> 4, m16 = lane & 15;
    const int wm = w & 1, wn = w >> 1;
    const int tm = bm * 2 + wm, tn = bn * 2 + wn;   // 64-row tile ids [0,128)

    __shared__ __align__(16) bf16_t As[128 * 32];   // 8 KB each
    __shared__ __align__(16) bf16_t Bs[128 * 32];

    // staging: lane -> (row r = lane&15, 16-B k-chunk c = lane>>4)
    // instruction (w, half h): global rows base + h*64 + w*16 + r, bytes c*16..+15
    // LDS slot: (h*4096 + w*1024) + lane*16  ->  chunk-column-major tile:
    //   LDS group g=(h*4+w) holds rows g*16..+15; within group, 16-B chunk of
    //   row r, k-chunk c sits at byte c*256 + r*16.
    const int sr = lane & 15;                 // row within 16-group
    const int sc = lane >> 4;                 // k-chunk 0..3 (8 bf16 each)
    const bf16_t* stA0 = Z + (size_t)(bm * 128 + w * 16 + sr) * DIM + sc * 8;
    const bf16_t* stA1 = stA0 + (size_t)64 * DIM;
    const bf16_t* stB0 = Z + (size_t)(bn * 128 + w * 16 + sr) * DIM + sc * 8;
    const bf16_t* stB1 = stB0 + (size_t)64 * DIM;

    // fragment read bases: frag(i) for wave row-tile: group wm*4+i, chunk q, row m16
    // byte addr = (wm*4+i)*1024 + q*256 + m16*16  -> contiguous 256 B per q-group
    const char* fraA = (const char*)As + wm * 4096 + q * 256 + m16 * 16;
    const char* fraB = (const char*)Bs + wn * 4096 + q * 256 + m16 * 16;

    floatx4 acc[4][4] = {};

    for (int kt = 0; kt < DIM; kt += 32) {
        __builtin_amdgcn_global_load_lds(GLOBAL_AS(stA0 + kt), LDS_AS((char*)As + w * 1024),        16, 0, 0);
        __builtin_amdgcn_global_load_lds(GLOBAL_AS(stA1 + kt), LDS_AS((char*)As + 4096 + w * 1024), 16, 0, 0);
        __builtin_amdgcn_global_load_lds(GLOBAL_AS(stB0 + kt), LDS_AS((char*)Bs + w * 1024),        16, 0, 0);
        __builtin_amdgcn_global_load_lds(GLOBAL_AS(stB1 + kt), LDS_AS((char*)Bs + 4096 + w * 1024), 16, 0, 0);
        __syncthreads();

        bf16x8 af[4], bfr[4];
        #pragma unroll
        for (int i = 0; i < 4; ++i) af[i]  = *(const bf16x8*)(fraA + i * 1024);
        #pragma unroll
        for (int j = 0; j < 4; ++j) bfr[j] = *(const bf16x8*)(fraB + j * 1024);
        #pragma unroll
        for (int i = 0; i < 4; ++i)
            #pragma unroll
            for (int j = 0; j < 4; ++j)
                acc[i][j] = __builtin_amdgcn_mfma_f32_16x16x32_bf16(af[i], bfr[j], acc[i][j], 0, 0, 0);
        __syncthreads();
    }

    // --- epilogue: C/D map row = i*16 + q*4 + r, col = j*16 + m16 (tile-local) ---
    const int rowBase = tm * 64 + q * 4;
    const int colBase = tn * 64 + m16;
    float negsum = 0.0f, possum = 0.0f;
    #pragma unroll
    for (int j = 0; j < 4; ++j) {
        const int cg = colBase + j * 16;
        float p = 1.0f;
        #pragma unroll
        for (int i = 0; i < 4; ++i) {
            const int rg0 = rowBase + i * 16;
            #pragma unroll
            for (int r = 0; r < 4; ++r) {
                const float s = acc[i][j][r];
                float e = __expf(s - LAM);
                if (rg0 + r == cg) e = 0.0f;          // mask main diagonal
                p *= (1.0f + e);
                if (cg == rg0 + r + N_ROWS)           // positive pair (k, k+N)
                    possum += log1pf(expf(-s + LAM));
            }
        }
        negsum += __logf(p);
    }
    // diag-block lower-triangle wave-tiles are redundant: weight 0; off-diag x2.
    const float wgt = (tn < tm) ? 0.0f : ((tm == tn) ? 1.0f : 2.0f);
    negsum *= wgt;

    #pragma unroll
    for (int off = 32; off; off >>= 1) {
        negsum += __shfl_xor(negsum, off);
        possum += __shfl_xor(possum, off);
    }
    if (lane == 0)
        atomicAdd(out, negsum * (1.0f / (12.0f * (float)N_ROWS))
                     + possum * (1.0f / (float)N_ROWS));
}

extern "C" void kernel_launch(void* const* d_in, const int* in_sizes, int n_in,
                              void* d_out, int out_size, void* d_ws, size_t ws_size,
                              hipStream_t stream) {
    const float* ei = (const float*)d_in[0];
    const float* ej = (const float*)d_in[1];
    float* out = (float*)d_out;
    bf16_t* Z = (bf16_t*)d_ws;                // 8192*512*2 B = 8 MB scratch

    normalize_kernel<<<2048, 256, 0, stream>>>(ei, ej, Z, out);
    simloss_kernel<<<dim3(64, 64), 256, 0, stream>>>(Z, out);
}

// Round 7
// 186.738 us; speedup vs baseline: 1.1198x; 1.1198x over previous
//
#include <hip/hip_runtime.h>
#include <hip/hip_bf16.h>
#include <math.h>

typedef __bf16 bf16_t;
typedef __bf16 bf16x8 __attribute__((ext_vector_type(8)));
typedef __bf16 bf16x4 __attribute__((ext_vector_type(4)));
typedef float floatx4 __attribute__((ext_vector_type(4)));
typedef long long i64x2 __attribute__((ext_vector_type(2)));

#define N_ROWS 4096
#define DIM 512
#define LAM 0.5f

#define GLOBAL_AS(p) ((const __attribute__((address_space(1))) void*)(p))
#define LDS_AS(p) ((__attribute__((address_space(3))) void*)(p))

// Z is stored TILED: 512 groups of 16 rows; each group is a contiguous 16 KB
// block with byte(g, kc, q, r16, j) = g*16384 + kc*1024 + q*256 + r16*16 + j*2
// where k = kc*32 + q*8 + j.  This layout is simultaneously (a) what the GEMM
// wants in LDS (fragment ds_read_b128 conflict-free: 16 lanes x contiguous
// 256 B per quad) and (b) stageable with fully-contiguous lane-monotone
// global_load_lds (lane i copies byte 16i of a 1 KB chunk).  R6 proved the
// conflict-free LDS image; R1-vs-R6 proved lane-monotone staging is mandatory;
// this layout delivers both.
//
// normalize: one block per 16-row group. Each wave L2-normalizes 4 rows,
// writes bf16 into an LDS image of the group (permuted positions), then the
// block copies the 16 KB out fully coalesced (64 B/thread).
__global__ __launch_bounds__(256) void normalize_kernel(
    const float* __restrict__ ei, const float* __restrict__ ej,
    unsigned char* __restrict__ Zt, float* __restrict__ out) {
    if (blockIdx.x == 0 && threadIdx.x == 0) out[0] = 0.0f;
    const int g = blockIdx.x;                 // group [0, 512)
    const int t = threadIdx.x, w = t >> 6, lane = t & 63;
    __shared__ __align__(16) unsigned char buf[16384];

    #pragma unroll
    for (int rr = 0; rr < 4; ++rr) {
        const int r16 = w * 4 + rr;           // row within group (waves disjoint)
        const int row = g * 16 + r16;         // [0, 8192)
        const float* __restrict__ src = (row < N_ROWS)
            ? (ei + (size_t)row * DIM)
            : (ej + (size_t)(row - N_ROWS) * DIM);
        const float4* src4 = (const float4*)src;
        float4 v0 = src4[lane];               // k = 4*lane .. +3
        float4 v1 = src4[lane + 64];          // k = 256 + 4*lane .. +3
        float s = v0.x*v0.x + v0.y*v0.y + v0.z*v0.z + v0.w*v0.w
                + v1.x*v1.x + v1.y*v1.y + v1.z*v1.z + v1.w*v1.w;
        #pragma unroll
        for (int off = 32; off; off >>= 1) s += __shfl_xor(s, off);
        const float r = rsqrtf(s);
        bf16x4 o0 = { (bf16_t)(v0.x*r), (bf16_t)(v0.y*r), (bf16_t)(v0.z*r), (bf16_t)(v0.w*r) };
        bf16x4 o1 = { (bf16_t)(v1.x*r), (bf16_t)(v1.y*r), (bf16_t)(v1.z*r), (bf16_t)(v1.w*r) };
        // k=4l: kc=l>>3, q=(l>>1)&3, j=(l&1)*4 -> byte addr within group:
        const int a0 = ((lane >> 3) << 10) + (((lane >> 1) & 3) << 8) + (r16 << 4) + ((lane & 1) << 3);
        *(bf16x4*)(buf + a0)        = o0;
        *(bf16x4*)(buf + a0 + 8192) = o1;     // v1: kc += 8
    }
    __syncthreads();
    // coalesced copy-out: 64 B per thread
    const i64x2* sp = (const i64x2*)buf;
    i64x2* dp = (i64x2*)(Zt + (size_t)g * 16384);
    #pragma unroll
    for (int u = 0; u < 4; ++u) dp[t * 4 + u] = sp[t * 4 + u];
}

// Fused S = Z.Z^T + loss.  R1 structure (bf16, BK=32, 2D upper-tri grid,
// 128x128 block, 4 waves 2x2, 16x16x32 bf16 MFMA).  Staging: 4 instructions
// per wave per K-step, each a fully-contiguous 1 KB group-chunk copy
// (lane-monotone, LDS = byte-for-byte global image).  Fragment reads:
// one ds_read_b128 per frag, conflict-free (R6-verified layout).
__global__ __launch_bounds__(256) void simloss_kernel(
    const unsigned char* __restrict__ Zt, float* __restrict__ out) {
    const int bm = blockIdx.x, bn = blockIdx.y;
    if (bn < bm) return;                      // symmetry: skip lower triangle
    const int t = threadIdx.x;
    const int w = t >> 6, lane = t & 63;
    const int q = lane >> 4, m16 = lane & 15;
    const int wm = w & 1, wn = w >> 1;
    const int tm = bm * 2 + wm, tn = bn * 2 + wn;   // 64-row tile ids [0,128)

    __shared__ __align__(16) unsigned char As[8192];   // 8 groups x 1 KB chunk
    __shared__ __align__(16) unsigned char Bs[8192];

    // staging sources: wave w stages groups {w, w+4} of A and of B
    const unsigned char* gA0 = Zt + ((size_t)(bm * 8 + w))     * 16384 + lane * 16;
    const unsigned char* gA1 = Zt + ((size_t)(bm * 8 + 4 + w)) * 16384 + lane * 16;
    const unsigned char* gB0 = Zt + ((size_t)(bn * 8 + w))     * 16384 + lane * 16;
    const unsigned char* gB1 = Zt + ((size_t)(bn * 8 + 4 + w)) * 16384 + lane * 16;
    unsigned char* lA0 = As + w * 1024;
    unsigned char* lA1 = As + (4 + w) * 1024;
    unsigned char* lB0 = Bs + w * 1024;
    unsigned char* lB1 = Bs + (4 + w) * 1024;

    // fragment bases: group (wm*4 + i) at i*1024; quad q at q*256; row m16*16
    const unsigned char* fraA = As + wm * 4096 + q * 256 + m16 * 16;
    const unsigned char* fraB = Bs + wn * 4096 + q * 256 + m16 * 16;

    floatx4 acc[4][4] = {};

    for (int kc = 0; kc < 16; ++kc) {         // K-chunks of 32
        const int ko = kc * 1024;
        __builtin_amdgcn_global_load_lds(GLOBAL_AS(gA0 + ko), LDS_AS(lA0), 16, 0, 0);
        __builtin_amdgcn_global_load_lds(GLOBAL_AS(gA1 + ko), LDS_AS(lA1), 16, 0, 0);
        __builtin_amdgcn_global_load_lds(GLOBAL_AS(gB0 + ko), LDS_AS(lB0), 16, 0, 0);
        __builtin_amdgcn_global_load_lds(GLOBAL_AS(gB1 + ko), LDS_AS(lB1), 16, 0, 0);
        __syncthreads();

        bf16x8 af[4], bfr[4];
        #pragma unroll
        for (int i = 0; i < 4; ++i) af[i]  = *(const bf16x8*)(fraA + i * 1024);
        #pragma unroll
        for (int j = 0; j < 4; ++j) bfr[j] = *(const bf16x8*)(fraB + j * 1024);
        #pragma unroll
        for (int i = 0; i < 4; ++i)
            #pragma unroll
            for (int j = 0; j < 4; ++j)
                acc[i][j] = __builtin_amdgcn_mfma_f32_16x16x32_bf16(af[i], bfr[j], acc[i][j], 0, 0, 0);
        __syncthreads();
    }

    // --- epilogue: C/D map row = i*16 + q*4 + r, col = j*16 + m16 (tile-local) ---
    const int rowBase = tm * 64 + q * 4;
    const int colBase = tn * 64 + m16;
    float negsum = 0.0f, possum = 0.0f;
    #pragma unroll
    for (int j = 0; j < 4; ++j) {
        const int cg = colBase + j * 16;
        float p = 1.0f;
        #pragma unroll
        for (int i = 0; i < 4; ++i) {
            const int rg0 = rowBase + i * 16;
            #pragma unroll
            for (int r = 0; r < 4; ++r) {
                const float s = acc[i][j][r];
                float e = __expf(s - LAM);
                if (rg0 + r == cg) e = 0.0f;          // mask main diagonal
                p *= (1.0f + e);
                if (cg == rg0 + r + N_ROWS)           // positive pair (k, k+N)
                    possum += log1pf(expf(-s + LAM));
            }
        }
        negsum += __logf(p);
    }
    // diag-block lower-triangle wave-tiles are redundant: weight 0; off-diag x2.
    const float wgt = (tn < tm) ? 0.0f : ((tm == tn) ? 1.0f : 2.0f);
    negsum *= wgt;

    #pragma unroll
    for (int off = 32; off; off >>= 1) {
        negsum += __shfl_xor(negsum, off);
        possum += __shfl_xor(possum, off);
    }
    if (lane == 0)
        atomicAdd(out, negsum * (1.0f / (12.0f * (float)N_ROWS))
                     + possum * (1.0f / (float)N_ROWS));
}

extern "C" void kernel_launch(void* const* d_in, const int* in_sizes, int n_in,
                              void* d_out, int out_size, void* d_ws, size_t ws_size,
                              hipStream_t stream) {
    const float* ei = (const float*)d_in[0];
    const float* ej = (const float*)d_in[1];
    float* out = (float*)d_out;
    unsigned char* Zt = (unsigned char*)d_ws;  // tiled bf16 Z: 8 MB scratch

    normalize_kernel<<<512, 256, 0, stream>>>(ei, ej, Zt, out);
    simloss_kernel<<<dim3(64, 64), 256, 0, stream>>>(Zt, out);
}

// Round 8
// 181.263 us; speedup vs baseline: 1.1536x; 1.0302x over previous
//
#include <hip/hip_runtime.h>
#include <hip/hip_bf16.h>
#include <hip/hip_fp8.h>
#include <math.h>

typedef float floatx4 __attribute__((ext_vector_type(4)));
typedef long long i64;

#define N_ROWS 4096
#define DIM 512
#define LAM 0.5f
#define NTILE 128         // 64-row tiles per dim (8192/64)
#define TILE_BYTES 32768  // 64 rows * 512 B (fp8)

#define GLOBAL_AS(p) ((const __attribute__((address_space(1))) void*)(p))
#define LDS_AS(p) ((__attribute__((address_space(3))) void*)(p))

// s_waitcnt imms (gfx9 layout: [3:0] vm_lo, [6:4] exp, [11:8] lgkm, [15:14] vm_hi)
#define WAITCNT_VM8   0x0F78   // vmcnt(8),   exp/lgkm no-wait
#define WAITCNT_VM0   0x0F70   // vmcnt(0),   exp/lgkm no-wait
#define WAITCNT_LGKM0 0xC07F   // lgkmcnt(0), vm/exp no-wait

__device__ __forceinline__ unsigned int pack4_fp8(float a, float b, float c, float d) {
    unsigned int u0 = __hip_cvt_float_to_fp8(a, __HIP_SATFINITE, __HIP_E4M3);
    unsigned int u1 = __hip_cvt_float_to_fp8(b, __HIP_SATFINITE, __HIP_E4M3);
    unsigned int u2 = __hip_cvt_float_to_fp8(c, __HIP_SATFINITE, __HIP_E4M3);
    unsigned int u3 = __hip_cvt_float_to_fp8(d, __HIP_SATFINITE, __HIP_E4M3);
    return u0 | (u1 << 8) | (u2 << 16) | (u3 << 24);
}

// Z stored TILED + SLOT-SWIZZLED fp8: tile t (64 rows), K-chunk kc (64 k):
//   byte(t, kc, r, p, b) = t*32768 + kc*4096 + r*64 + p*8 + b
// where logical slot s = 2*q + h  (k = kc*64 + h*32 + q*8 + b) is stored at
// physical p = s ^ (r & 7).  Properties: (a) GEMM staging of one (t,kc) block
// = 4 contiguous lane-monotone 1 KB copies; (b) fragment ds_read_b64 at fixed
// (q,h) across m16 spreads over all banks -> exactly 2-way (free, m136).
__global__ __launch_bounds__(256) void normalize_kernel(
    const float* __restrict__ ei, const float* __restrict__ ej,
    unsigned char* __restrict__ Zt, float* __restrict__ out) {
    if (blockIdx.x == 0 && threadIdx.x == 0) out[0] = 0.0f;
    const int w = threadIdx.x >> 6, lane = threadIdx.x & 63;
    const int row = blockIdx.x * 4 + w;        // [0, 8192)
    const int tt = row >> 6, r = row & 63;
    const float* __restrict__ src = (row < N_ROWS)
        ? (ei + (size_t)row * DIM)
        : (ej + (size_t)(row - N_ROWS) * DIM);
    const float4* s4 = (const float4*)src;
    float4 v0 = s4[lane];                      // k = 4*lane .. +3
    float4 v1 = s4[lane + 64];                 // k = 256 + 4*lane .. +3
    float s = v0.x*v0.x + v0.y*v0.y + v0.z*v0.z + v0.w*v0.w
            + v1.x*v1.x + v1.y*v1.y + v1.z*v1.z + v1.w*v1.w;
    #pragma unroll
    for (int off = 32; off; off >>= 1) s += __shfl_xor(s, off);
    const float rn = rsqrtf(s);

    __shared__ __align__(8) unsigned char buf[4][512];   // per-wave row image
    {
        int k0 = 4 * lane;
        int p0 = (((( k0 >> 3) & 3) << 1) | ((k0 >> 5) & 1)) ^ (r & 7);
        *(unsigned int*)(buf[w] + (k0 >> 6) * 64 + p0 * 8 + (k0 & 7)) =
            pack4_fp8(v0.x*rn, v0.y*rn, v0.z*rn, v0.w*rn);
        int k1 = 256 + 4 * lane;
        int p1 = ((((k1 >> 3) & 3) << 1) | ((k1 >> 5) & 1)) ^ (r & 7);
        *(unsigned int*)(buf[w] + (k1 >> 6) * 64 + p1 * 8 + (k1 & 7)) =
            pack4_fp8(v1.x*rn, v1.y*rn, v1.z*rn, v1.w*rn);
    }
    // copy out: lane -> (kc = lane>>3, slot = lane&7), 8 B each (phys->phys)
    const int kc = lane >> 3, sl = lane & 7;
    *(i64*)(Zt + (size_t)tt * TILE_BYTES + kc * 4096 + r * 64 + sl * 8) =
        *(const i64*)(buf[w] + kc * 64 + sl * 8);
}

// Fused S = Z.Z^T (fp8 16x16x32 MFMA) + loss.  ONE WAVE PER BLOCK, one 64x64
// tile per wave, LDS private to the wave -> NO __syncthreads in the K-loop.
// Double-buffered: issue 8 loads (4 KB A + 4 KB B) for kc+1, then
// s_waitcnt vmcnt(8) so only the OLDEST 8 (kc's tile) must land before the
// ds_reads — prefetch stays in flight across compute (the fine-grained-vmcnt
// pipeline a barrier'd block structure cannot express).  Triangular grid over
// 128x128 tiles; tn>tm weighted x2; positives on tn==tm+64 local diagonals.
__global__ __launch_bounds__(64) void simloss_kernel(
    const unsigned char* __restrict__ Zt, float* __restrict__ out) {
    // --- triangular decode, NT = 128 ---
    const int id = blockIdx.x;
    int tm = (int)((2*NTILE + 1 - sqrtf((float)((2*NTILE+1)*(2*NTILE+1)) - 8.0f * (float)id)) * 0.5f);
    if (tm < 0) tm = 0; if (tm > NTILE-1) tm = NTILE-1;
    while ((tm + 1) * NTILE - ((tm + 1) * tm) / 2 <= id) ++tm;
    while (tm * NTILE - (tm * (tm - 1)) / 2 > id) --tm;
    const int tn = tm + (id - (tm * NTILE - (tm * (tm - 1)) / 2));

    const int lane = threadIdx.x;
    const int q = lane >> 4, m16 = lane & 15;

    __shared__ __align__(16) unsigned char As[2][4096];
    __shared__ __align__(16) unsigned char Bs[2][4096];

    const unsigned char* gA = Zt + (size_t)tm * TILE_BYTES + lane * 16;
    const unsigned char* gB = Zt + (size_t)tn * TILE_BYTES + lane * 16;

    // physical slot offsets for (q, h): r&7 == m16&7 for every frag row
    const int p0 = ((q << 1) | 0) ^ (m16 & 7);   // k-half 0 (k = q*8..)
    const int p1 = ((q << 1) | 1) ^ (m16 & 7);   // k-half 1 (k = 32+q*8..)

    floatx4 acc[4][4] = {};

    // prologue: stage kc=0 into buffer 0
    #pragma unroll
    for (int l = 0; l < 4; ++l) {
        __builtin_amdgcn_global_load_lds(GLOBAL_AS(gA + l * 1024), LDS_AS(As[0] + l * 1024), 16, 0, 0);
        __builtin_amdgcn_global_load_lds(GLOBAL_AS(gB + l * 1024), LDS_AS(Bs[0] + l * 1024), 16, 0, 0);
    }

    #pragma unroll
    for (int kc = 0; kc < 8; ++kc) {
        const int b = kc & 1;
        if (kc < 7) {
            const int nb = b ^ 1, ko = (kc + 1) * 4096;
            #pragma unroll
            for (int l = 0; l < 4; ++l) {
                __builtin_amdgcn_global_load_lds(GLOBAL_AS(gA + ko + l * 1024), LDS_AS(As[nb] + l * 1024), 16, 0, 0);
                __builtin_amdgcn_global_load_lds(GLOBAL_AS(gB + ko + l * 1024), LDS_AS(Bs[nb] + l * 1024), 16, 0, 0);
            }
            __builtin_amdgcn_s_waitcnt(WAITCNT_VM8);   // oldest 8 (tile kc) done
        } else {
            __builtin_amdgcn_s_waitcnt(WAITCNT_VM0);
        }
        __builtin_amdgcn_sched_barrier(0);

        i64 a0[4], a1[4], b0[4], b1[4];
        #pragma unroll
        for (int i = 0; i < 4; ++i) {
            const int rb = (i * 16 + m16) * 64;
            a0[i] = *(const i64*)(As[b] + rb + p0 * 8);
            a1[i] = *(const i64*)(As[b] + rb + p1 * 8);
            b0[i] = *(const i64*)(Bs[b] + rb + p0 * 8);
            b1[i] = *(const i64*)(Bs[b] + rb + p1 * 8);
        }
        #pragma unroll
        for (int i = 0; i < 4; ++i)
            #pragma unroll
            for (int j = 0; j < 4; ++j) {
                acc[i][j] = __builtin_amdgcn_mfma_f32_16x16x32_fp8_fp8(a0[i], b0[j], acc[i][j], 0, 0, 0);
                acc[i][j] = __builtin_amdgcn_mfma_f32_16x16x32_fp8_fp8(a1[i], b1[j], acc[i][j], 0, 0, 0);
            }
        __builtin_amdgcn_s_waitcnt(WAITCNT_LGKM0);     // ds_reads done before DMA overwrites
        __builtin_amdgcn_sched_barrier(0);
    }

    // --- epilogue: C/D map row = i*16 + q*4 + rr, col = j*16 + m16 (tile-local) ---
    const int rowBase = tm * 64 + q * 4;
    const int colBase = tn * 64 + m16;
    float negsum = 0.0f, possum = 0.0f;
    #pragma unroll
    for (int j = 0; j < 4; ++j) {
        const int cg = colBase + j * 16;
        float p = 1.0f;
        #pragma unroll
        for (int i = 0; i < 4; ++i) {
            const int rg0 = rowBase + i * 16;
            #pragma unroll
            for (int rr = 0; rr < 4; ++rr) {
                const float sv = acc[i][j][rr];
                float e = __expf(sv - LAM);
                if (rg0 + rr == cg) e = 0.0f;         // mask main diagonal
                p *= (1.0f + e);
                if (cg == rg0 + rr + N_ROWS)          // positive pair (k, k+N)
                    possum += log1pf(expf(-sv + LAM));
            }
        }
        negsum += __logf(p);
    }
    if (tn != tm) negsum *= 2.0f;                     // symmetric tile (tn, tm)

    #pragma unroll
    for (int off = 32; off; off >>= 1) {
        negsum += __shfl_xor(negsum, off);
        possum += __shfl_xor(possum, off);
    }
    if (lane == 0)
        atomicAdd(out, negsum * (1.0f / (12.0f * (float)N_ROWS))
                     + possum * (1.0f / (float)N_ROWS));
}

extern "C" void kernel_launch(void* const* d_in, const int* in_sizes, int n_in,
                              void* d_out, int out_size, void* d_ws, size_t ws_size,
                              hipStream_t stream) {
    const float* ei = (const float*)d_in[0];
    const float* ej = (const float*)d_in[1];
    float* out = (float*)d_out;
    unsigned char* Zt = (unsigned char*)d_ws;  // tiled fp8 Z: 4 MB scratch

    normalize_kernel<<<2048, 256, 0, stream>>>(ei, ej, Zt, out);
    simloss_kernel<<<NTILE * (NTILE + 1) / 2, 64, 0, stream>>>(Zt, out);
}